// Round 1
// baseline (4412.356 us; speedup 1.0000x reference)
//
#include <hip/hip_runtime.h>
#include <hip/hip_bf16.h>
#include <stdint.h>

#define E_ 8
#define L_ 12
#define D_ 768
#define H_ 12
#define S_ 512
#define B_ 32
#define BS_ (B_*S_)   // 16384

typedef __attribute__((ext_vector_type(4))) float floatx4;
typedef __attribute__((ext_vector_type(8))) __bf16 bf16x8;

__device__ __forceinline__ __bf16 f2bf(float f) {
  unsigned u = __builtin_bit_cast(unsigned, f);
  u += 0x7fffu + ((u >> 16) & 1u);           // RNE
  unsigned short h = (unsigned short)(u >> 16);
  return __builtin_bit_cast(__bf16, h);
}

__device__ __forceinline__ void async16(const void* g, void* l) {
  __builtin_amdgcn_global_load_lds((__attribute__((address_space(1))) void*)g,
                                   (__attribute__((address_space(3))) void*)l,
                                   16, 0, 0);
}

// ---------------- routing: argmax logits of sample B-1 ----------------
__global__ void routing_kernel(const float* __restrict__ hidden,
                               const float* __restrict__ rw,
                               int* __restrict__ e_out) {
  __shared__ float pooled[D_];
  __shared__ float logits[E_];
  int tid = threadIdx.x;
  for (int d = tid; d < D_; d += 256) {
    float s = 0.f;
    const float* p = hidden + (size_t)(B_-1)*S_*D_ + d;
    for (int ss = 0; ss < S_; ++ss) s += p[(size_t)ss*D_];
    pooled[d] = s;  // positive scale factor irrelevant for argmax
  }
  __syncthreads();
  if (tid < E_) {
    float s = 0.f;
    for (int d = 0; d < D_; ++d) s += pooled[d] * rw[d*E_ + tid];
    logits[tid] = s;
  }
  __syncthreads();
  if (tid == 0) {
    int best = 0; float bvv = logits[0];
    for (int e = 1; e < E_; ++e) if (logits[e] > bvv) { bvv = logits[e]; best = e; }
    e_out[0] = best;
  }
}

// ---------------- fp32 -> bf16 convert (n multiple of 2048) ----------------
__global__ void convert_bf16_kernel(const float* __restrict__ src, __bf16* __restrict__ dst) {
  size_t i = ((size_t)blockIdx.x*256 + threadIdx.x)*8;
  __bf16 r[8];
#pragma unroll
  for (int j = 0; j < 8; ++j) r[j] = f2bf(src[i+j]);
  *(bf16x8*)(dst + i) = *(bf16x8*)r;
}

// Wk [L][768][768] fp32 -> rows 768..1535 of wqkv [L][2304][768] bf16
__global__ void convert_wk_kernel(const float* __restrict__ wk, __bf16* __restrict__ wqkv) {
  size_t i = ((size_t)blockIdx.x*256 + threadIdx.x)*8;
  int l = (int)(i / (D_*D_));
  int rem = (int)(i % (D_*D_));
  int n = rem / D_, k = rem % D_;
  __bf16 r[8];
#pragma unroll
  for (int j = 0; j < 8; ++j) r[j] = f2bf(wk[i+j]);
  *(bf16x8*)(wqkv + (size_t)l*2304*D_ + (size_t)(768+n)*D_ + k) = *(bf16x8*)r;
}

// ---------------- TT adapter build: Wq_a / Wv_a -> wqkv bf16 ----------------
// W_tt[out][in] = sum_o M2[out][o] * R[o][in]
//   out=(j,l2,n): j*64+l2*8+n ; in=(p,r,t): p*96+r*12+t
__global__ void tt_prep_kernel(
    const float* __restrict__ qc0, const float* __restrict__ qc1, const float* __restrict__ qc2,
    const float* __restrict__ qc3, const float* __restrict__ qc4, const float* __restrict__ qc5,
    const float* __restrict__ vc0, const float* __restrict__ vc1, const float* __restrict__ vc2,
    const float* __restrict__ vc3, const float* __restrict__ vc4, const float* __restrict__ vc5,
    const float* __restrict__ Wq, const float* __restrict__ Wv,
    const int* __restrict__ e_idx, __bf16* __restrict__ wqkv) {
  const int l = blockIdx.x;
  const int pre = blockIdx.y;         // 0 = q, 1 = v
  const int tid = threadIdx.x;
  const int e = e_idx[0];
  const float* c0 = (pre ? vc0 : qc0) + (size_t)(e*L_ + l)*96;   // [12][8]
  const float* c1 = (pre ? vc1 : qc1) + (size_t)(e*L_ + l)*512;  // [8][8][8]
  const float* c2 = (pre ? vc2 : qc2) + (size_t)(e*L_ + l)*512;
  const float* c3 = (pre ? vc3 : qc3) + (size_t)(e*L_ + l)*512;
  const float* c4 = (pre ? vc4 : qc4) + (size_t)(e*L_ + l)*512;
  const float* c5 = (pre ? vc5 : qc5) + (size_t)(e*L_ + l)*96;   // [8][12]
  __shared__ float M1[768];   // [j][l2][m]
  __shared__ float R2[768];   // [q][r][t]
  __shared__ float M2[6144];  // [out][o]
  __shared__ float Rm[6144];  // [o][in]
  for (int idx = tid; idx < 768; idx += 256) {
    int j = idx >> 6, rem = idx & 63, l2 = rem >> 3, m = rem & 7;
    float s = 0.f;
    for (int k = 0; k < 8; ++k) s += c0[j*8 + k] * c1[k*64 + l2*8 + m];
    M1[idx] = s;
    int qq = idx / 96, rem2 = idx % 96, rr = rem2 / 12, t = rem2 % 12;
    float s2 = 0.f;
    for (int si = 0; si < 8; ++si) s2 += c4[qq*64 + rr*8 + si] * c5[si*12 + t];
    R2[idx] = s2;
  }
  __syncthreads();
  for (int idx = tid; idx < 6144; idx += 256) {
    int o = idx & 7, n = (idx >> 3) & 7, jl = idx >> 6;
    float s = 0.f;
    for (int m = 0; m < 8; ++m) s += M1[jl*8 + m] * c2[m*64 + n*8 + o];
    M2[idx] = s;
    int o2 = idx / 768, inp = idx % 768, p = inp / 96, rt = inp % 96;
    float s2 = 0.f;
    for (int qq = 0; qq < 8; ++qq) s2 += c3[o2*64 + p*8 + qq] * R2[qq*96 + rt];
    Rm[idx] = s2;
  }
  __syncthreads();
  const float* Wbase = (pre ? Wv : Wq) + (size_t)l*D_*D_;
  __bf16* dst = wqkv + (size_t)l*2304*D_ + (pre ? (size_t)1536*D_ : 0);
  for (int idx = tid; idx < D_*D_; idx += 256) {
    int outr = idx / 768, inp = idx % 768;
    float s = 0.f;
#pragma unroll
    for (int o = 0; o < 8; ++o) s += M2[outr*8 + o] * Rm[o*768 + inp];
    dst[idx] = f2bf(Wbase[idx] + 8.0f * s);
  }
}

// ---------------- bf16 MFMA GEMM: C[M][Nw] = A[M][768] * Bw[Nw][768]^T + bias ----------------
template<bool OUTBF>
__global__ __launch_bounds__(256) void gemm_bt(
    const __bf16* __restrict__ A, const __bf16* __restrict__ Bw,
    const float* __restrict__ bq, const float* __restrict__ bk, const float* __restrict__ bvp,
    __bf16* __restrict__ outb, float* __restrict__ outf, int Nw) {
  const int K = D_;
  __shared__ __align__(16) __bf16 As[128*64];
  __shared__ __align__(16) __bf16 Bs[128*64];
  const int tid = threadIdx.x;
  const int w = tid >> 6, lane = tid & 63;
  const int quad = lane >> 4, l16 = lane & 15;
  const int wr = w >> 1, wc = w & 1;
  const size_t mblk = (size_t)blockIdx.y * 128;
  const size_t nblk = (size_t)blockIdx.x * 128;
  const __bf16* Ab = A + mblk * K;
  const __bf16* Bb = Bw + nblk * K;
  const int lrow = lane >> 3;        // 0..7
  const int scol = (lane & 7) * 8;   // element offset in K
  floatx4 acc[4][4];
#pragma unroll
  for (int i = 0; i < 4; ++i)
#pragma unroll
    for (int j = 0; j < 4; ++j) acc[i][j] = {0.f,0.f,0.f,0.f};

  for (int k0 = 0; k0 < K; k0 += 64) {
    __syncthreads();
#pragma unroll
    for (int i = 0; i < 4; ++i) {
      const int chunk = w*4 + i;           // wave-uniform
      const int row = chunk*8 + lrow;
      async16(Ab + (size_t)row*K + k0 + scol, &As[chunk*512]);
      async16(Bb + (size_t)row*K + k0 + scol, &Bs[chunk*512]);
    }
    __syncthreads();
#pragma unroll
    for (int kk = 0; kk < 64; kk += 32) {
      bf16x8 af[4], bfr[4];
#pragma unroll
      for (int i = 0; i < 4; ++i) af[i]  = *(const bf16x8*)&As[(wr*64 + i*16 + l16)*64 + kk + quad*8];
#pragma unroll
      for (int j = 0; j < 4; ++j) bfr[j] = *(const bf16x8*)&Bs[(wc*64 + j*16 + l16)*64 + kk + quad*8];
#pragma unroll
      for (int i = 0; i < 4; ++i)
#pragma unroll
        for (int j = 0; j < 4; ++j)
          acc[i][j] = __builtin_amdgcn_mfma_f32_16x16x32_bf16(af[i], bfr[j], acc[i][j], 0, 0, 0);
    }
  }
  const float* bias = bq;
  if (Nw == 2304) bias = (blockIdx.x < 6) ? bq : (blockIdx.x < 12 ? bk : bvp);
#pragma unroll
  for (int i = 0; i < 4; ++i) {
#pragma unroll
    for (int j = 0; j < 4; ++j) {
      const int ncol = (int)nblk + wc*64 + j*16 + l16;
      const float bval = bias[ncol % 768];
#pragma unroll
      for (int r = 0; r < 4; ++r) {
        const int mrow = (int)mblk + wr*64 + i*16 + quad*4 + r;
        float v = acc[i][j][r] + bval;
        if (OUTBF) outb[(size_t)mrow*Nw + ncol] = f2bf(v);
        else       outf[(size_t)mrow*Nw + ncol] = v;
      }
    }
  }
}

// ---------------- V transpose: qkv V-seg [b,s,h,d] -> vt [b,h,d,s] ----------------
__global__ void transpose_v_kernel(const __bf16* __restrict__ qkv, __bf16* __restrict__ vt) {
  __shared__ __bf16 tile[64*66];   // pad 66: conflict-free strided read
  const int tid = threadIdx.x;
  const int s0 = blockIdx.x * 64;
  const int h = blockIdx.y, b = blockIdx.z;
#pragma unroll
  for (int p = 0; p < 16; ++p) {
    int idx = p*256 + tid;
    int sl = idx >> 6, d = idx & 63;
    tile[sl*66 + d] = qkv[(size_t)(b*S_ + s0 + sl)*2304 + 1536 + h*64 + d];
  }
  __syncthreads();
#pragma unroll
  for (int p = 0; p < 16; ++p) {
    int idx = p*256 + tid;
    int d = idx >> 6, sl = idx & 63;
    vt[(size_t)((b*H_ + h)*64 + d)*S_ + s0 + sl] = tile[sl*66 + d];
  }
}

// ---------------- flash attention: per (b,h,64-row Q tile) ----------------
__global__ __launch_bounds__(256) void flash_kernel(const __bf16* __restrict__ qkv,
                                                    const __bf16* __restrict__ vt,
                                                    __bf16* __restrict__ ctx) {
  __shared__ __align__(16) __bf16 Qs[64*64];   // [q][d]
  __shared__ __align__(16) __bf16 Ks[64*64];   // [kv][d]
  __shared__ __align__(16) __bf16 Vts[64*64];  // [d][kv]
  __shared__ __align__(16) __bf16 Ps[64*64];   // [q][kv]
  const int tid = threadIdx.x;
  const int w = tid >> 6, lane = tid & 63;
  const int quad = lane >> 4, l16 = lane & 15;
  const int q0 = blockIdx.x * 64;
  const int h = blockIdx.y, b = blockIdx.z;
  const int lrow = lane >> 3;
  const int lcol = (lane & 7) * 8;

  // stage Q once (8 chunks of 1KB; wave w handles 2w, 2w+1)
#pragma unroll
  for (int i = 0; i < 2; ++i) {
    const int chunk = w*2 + i;
    const int row = chunk*8 + lrow;
    async16(qkv + (size_t)(b*S_ + q0 + row)*2304 + h*64 + lcol, &Qs[chunk*512]);
  }

  floatx4 acc_o[4];
#pragma unroll
  for (int j = 0; j < 4; ++j) acc_o[j] = {0.f,0.f,0.f,0.f};
  float m_prev[4], l_prev[4];
#pragma unroll
  for (int r = 0; r < 4; ++r) { m_prev[r] = -__builtin_inff(); l_prev[r] = 0.f; }

  for (int kt = 0; kt < 8; ++kt) {
    __syncthreads();
#pragma unroll
    for (int i = 0; i < 2; ++i) {
      const int chunk = w*2 + i;
      const int row = chunk*8 + lrow;
      async16(qkv + (size_t)(b*S_ + kt*64 + row)*2304 + 768 + h*64 + lcol, &Ks[chunk*512]);
      async16(vt + (size_t)((b*H_ + h)*64 + row)*S_ + kt*64 + lcol, &Vts[chunk*512]);
    }
    __syncthreads();
    // S = Q K^T (wave w owns rows w*16..w*16+15)
    floatx4 sacc[4];
#pragma unroll
    for (int j = 0; j < 4; ++j) sacc[j] = {0.f,0.f,0.f,0.f};
#pragma unroll
    for (int kk = 0; kk < 64; kk += 32) {
      bf16x8 aq = *(const bf16x8*)&Qs[(w*16 + l16)*64 + kk + quad*8];
#pragma unroll
      for (int j = 0; j < 4; ++j) {
        bf16x8 bk_ = *(const bf16x8*)&Ks[(j*16 + l16)*64 + kk + quad*8];
        sacc[j] = __builtin_amdgcn_mfma_f32_16x16x32_bf16(aq, bk_, sacc[j], 0, 0, 0);
      }
    }
    float sv[4][4];
#pragma unroll
    for (int j = 0; j < 4; ++j)
#pragma unroll
      for (int r = 0; r < 4; ++r) sv[j][r] = sacc[j][r] * 0.125f;
    float mnew[4], alpha[4], rsum[4];
#pragma unroll
    for (int r = 0; r < 4; ++r) {
      float mv = fmaxf(fmaxf(sv[0][r], sv[1][r]), fmaxf(sv[2][r], sv[3][r]));
#pragma unroll
      for (int off = 1; off < 16; off <<= 1) mv = fmaxf(mv, __shfl_xor(mv, off));
      float mn = fmaxf(m_prev[r], mv);
      mnew[r] = mn;
      alpha[r] = __expf(m_prev[r] - mn);
      rsum[r] = 0.f;
    }
#pragma unroll
    for (int j = 0; j < 4; ++j)
#pragma unroll
      for (int r = 0; r < 4; ++r) {
        float p = __expf(sv[j][r] - mnew[r]);
        rsum[r] += p;
        Ps[(w*16 + quad*4 + r)*64 + j*16 + l16] = f2bf(p);  // same-wave rows only
      }
#pragma unroll
    for (int r = 0; r < 4; ++r) {
      float s = rsum[r];
#pragma unroll
      for (int off = 1; off < 16; off <<= 1) s += __shfl_xor(s, off);
      l_prev[r] = l_prev[r]*alpha[r] + s;
      m_prev[r] = mnew[r];
    }
#pragma unroll
    for (int j = 0; j < 4; ++j)
#pragma unroll
      for (int r = 0; r < 4; ++r) acc_o[j][r] = acc_o[j][r] * alpha[r];
    // O += P V   (DS ops are in-order per wave: P write->read safe without barrier)
#pragma unroll
    for (int kk = 0; kk < 64; kk += 32) {
      bf16x8 ap = *(const bf16x8*)&Ps[(w*16 + l16)*64 + kk + quad*8];
#pragma unroll
      for (int j = 0; j < 4; ++j) {
        bf16x8 bv_ = *(const bf16x8*)&Vts[(j*16 + l16)*64 + kk + quad*8];
        acc_o[j] = __builtin_amdgcn_mfma_f32_16x16x32_bf16(ap, bv_, acc_o[j], 0, 0, 0);
      }
    }
  }
#pragma unroll
  for (int j = 0; j < 4; ++j) {
    const int d = j*16 + l16;
#pragma unroll
    for (int r = 0; r < 4; ++r) {
      const int q = q0 + w*16 + quad*4 + r;
      float v = acc_o[j][r] / l_prev[r];
      ctx[(size_t)(b*S_ + q)*D_ + h*64 + d] = f2bf(v);
    }
  }
}

// ---------------- residual + LayerNorm (fp32), writes fp32 master + bf16 copy ----------------
__global__ __launch_bounds__(256) void ln_kernel(const float* __restrict__ resid,
                                                 const float* __restrict__ proj,
                                                 const float* __restrict__ gamma,
                                                 const float* __restrict__ beta,
                                                 float* __restrict__ xout,
                                                 __bf16* __restrict__ xbf) {
  const int row = blockIdx.x;
  const int tid = threadIdx.x;
  const int w = tid >> 6, lane = tid & 63;
  __shared__ float red[4];
  float v[3]; int dd[3];
#pragma unroll
  for (int i = 0; i < 3; ++i) {
    int d = tid + i*256; dd[i] = d;
    v[i] = resid[(size_t)row*D_ + d] + proj[(size_t)row*D_ + d];
  }
  float s = v[0] + v[1] + v[2];
#pragma unroll
  for (int off = 32; off; off >>= 1) s += __shfl_xor(s, off);
  if (lane == 0) red[w] = s;
  __syncthreads();
  float mu = (red[0]+red[1]+red[2]+red[3]) * (1.f/768.f);
  __syncthreads();
  float q = 0.f;
#pragma unroll
  for (int i = 0; i < 3; ++i) { float d = v[i]-mu; q += d*d; }
#pragma unroll
  for (int off = 32; off; off >>= 1) q += __shfl_xor(q, off);
  if (lane == 0) red[w] = q;
  __syncthreads();
  float var = (red[0]+red[1]+red[2]+red[3]) * (1.f/768.f);
  float rs = rsqrtf(var + 1e-12f);
#pragma unroll
  for (int i = 0; i < 3; ++i) {
    float o = (v[i]-mu)*rs*gamma[dd[i]] + beta[dd[i]];
    xout[(size_t)row*D_ + dd[i]] = o;
    xbf[(size_t)row*D_ + dd[i]] = f2bf(o);
  }
}

extern "C" void kernel_launch(void* const* d_in, const int* in_sizes, int n_in,
                              void* d_out, int out_size, void* d_ws, size_t ws_size,
                              hipStream_t stream) {
  const float* hidden = (const float*)d_in[0];
  const float* router = (const float*)d_in[1];
  const float* qc[6]; const float* vc[6];
  for (int i = 0; i < 6; ++i) qc[i] = (const float*)d_in[2+i];
  for (int i = 0; i < 6; ++i) vc[i] = (const float*)d_in[8+i];
  const float* Wq = (const float*)d_in[14];
  const float* Wk = (const float*)d_in[15];
  const float* Wv = (const float*)d_in[16];
  const float* Wo = (const float*)d_in[17];
  const float* bq = (const float*)d_in[18];
  const float* bk = (const float*)d_in[19];
  const float* bv = (const float*)d_in[20];
  const float* bo = (const float*)d_in[21];
  const float* lns = (const float*)d_in[22];
  const float* lnb = (const float*)d_in[23];
  float* out = (float*)d_out;

  char* ws = (char*)d_ws;
  size_t off = 0;
  auto alloc = [&](size_t bytes) -> void* {
    off = (off + 255) & ~(size_t)255;
    void* p = ws + off; off += bytes; return p;
  };
  int*    e_idx = (int*)   alloc(4);
  __bf16* xbf   = (__bf16*)alloc((size_t)BS_*D_*2);
  __bf16* qkv   = (__bf16*)alloc((size_t)BS_*2304*2);
  __bf16* vt    = (__bf16*)alloc((size_t)B_*H_*64*S_*2);
  __bf16* ctx   = (__bf16*)alloc((size_t)BS_*D_*2);
  float*  proj  = (float*) alloc((size_t)BS_*D_*4);
  __bf16* wqkv  = (__bf16*)alloc((size_t)L_*2304*D_*2);
  __bf16* wobf  = (__bf16*)alloc((size_t)L_*D_*D_*2);
  (void)ws_size; (void)in_sizes; (void)n_in; (void)out_size;

  routing_kernel<<<1, 256, 0, stream>>>(hidden, router, e_idx);
  convert_bf16_kernel<<<(BS_*D_)/2048, 256, 0, stream>>>(hidden, xbf);
  tt_prep_kernel<<<dim3(L_,2), 256, 0, stream>>>(qc[0],qc[1],qc[2],qc[3],qc[4],qc[5],
                                                 vc[0],vc[1],vc[2],vc[3],vc[4],vc[5],
                                                 Wq, Wv, e_idx, wqkv);
  convert_wk_kernel<<<(L_*D_*D_)/2048, 256, 0, stream>>>(Wk, wqkv);
  convert_bf16_kernel<<<(L_*D_*D_)/2048, 256, 0, stream>>>(Wo, wobf);

  for (int l = 0; l < L_; ++l) {
    gemm_bt<true><<<dim3(18,128), 256, 0, stream>>>(xbf, wqkv + (size_t)l*2304*D_,
        bq + l*D_, bk + l*D_, bv + l*D_, qkv, nullptr, 2304);
    transpose_v_kernel<<<dim3(8,H_,B_), 256, 0, stream>>>(qkv, vt);
    flash_kernel<<<dim3(8,H_,B_), 256, 0, stream>>>(qkv, vt, ctx);
    gemm_bt<false><<<dim3(6,128), 256, 0, stream>>>(ctx, wobf + (size_t)l*D_*D_,
        bo + l*D_, nullptr, nullptr, nullptr, proj, 768);
    ln_kernel<<<BS_, 256, 0, stream>>>(l == 0 ? hidden : out, proj,
        lns + l*D_, lnb + l*D_, out, xbf);
  }
}

// Round 2
// 3884.483 us; speedup vs baseline: 1.1359x; 1.1359x over previous
//
#include <hip/hip_runtime.h>
#include <hip/hip_bf16.h>
#include <stdint.h>

#define E_ 8
#define L_ 12
#define D_ 768
#define H_ 12
#define S_ 512
#define B_ 32
#define BS_ (B_*S_)   // 16384

typedef __attribute__((ext_vector_type(4))) float floatx4;
typedef __attribute__((ext_vector_type(8))) __bf16 bf16x8;

__device__ __forceinline__ __bf16 f2bf(float f) {
  unsigned u = __builtin_bit_cast(unsigned, f);
  u += 0x7fffu + ((u >> 16) & 1u);           // RNE
  unsigned short h = (unsigned short)(u >> 16);
  return __builtin_bit_cast(__bf16, h);
}

__device__ __forceinline__ void async16(const void* g, void* l) {
  __builtin_amdgcn_global_load_lds((__attribute__((address_space(1))) void*)g,
                                   (__attribute__((address_space(3))) void*)l,
                                   16, 0, 0);
}

// ---------------- routing: argmax logits of sample B-1 ----------------
__global__ void routing_kernel(const float* __restrict__ hidden,
                               const float* __restrict__ rw,
                               int* __restrict__ e_out) {
  __shared__ float pooled[D_];
  __shared__ float logits[E_];
  int tid = threadIdx.x;
  for (int d = tid; d < D_; d += 256) {
    float s = 0.f;
    const float* p = hidden + (size_t)(B_-1)*S_*D_ + d;
    for (int ss = 0; ss < S_; ++ss) s += p[(size_t)ss*D_];
    pooled[d] = s;  // positive scale factor irrelevant for argmax
  }
  __syncthreads();
  if (tid < E_) {
    float s = 0.f;
    for (int d = 0; d < D_; ++d) s += pooled[d] * rw[d*E_ + tid];
    logits[tid] = s;
  }
  __syncthreads();
  if (tid == 0) {
    int best = 0; float bvv = logits[0];
    for (int e = 1; e < E_; ++e) if (logits[e] > bvv) { bvv = logits[e]; best = e; }
    e_out[0] = best;
  }
}

// ---------------- fp32 -> bf16 convert (n multiple of 2048) ----------------
__global__ void convert_bf16_kernel(const float* __restrict__ src, __bf16* __restrict__ dst) {
  size_t i = ((size_t)blockIdx.x*256 + threadIdx.x)*8;
  __bf16 r[8];
#pragma unroll
  for (int j = 0; j < 8; ++j) r[j] = f2bf(src[i+j]);
  *(bf16x8*)(dst + i) = *(bf16x8*)r;
}

// Wk [L][768][768] fp32 -> rows 768..1535 of wqkv [L][2304][768] bf16
__global__ void convert_wk_kernel(const float* __restrict__ wk, __bf16* __restrict__ wqkv) {
  size_t i = ((size_t)blockIdx.x*256 + threadIdx.x)*8;
  int l = (int)(i / (D_*D_));
  int rem = (int)(i % (D_*D_));
  int n = rem / D_, k = rem % D_;
  __bf16 r[8];
#pragma unroll
  for (int j = 0; j < 8; ++j) r[j] = f2bf(wk[i+j]);
  *(bf16x8*)(wqkv + (size_t)l*2304*D_ + (size_t)(768+n)*D_ + k) = *(bf16x8*)r;
}

// ---------------- TT adapter build: Wq_a / Wv_a -> wqkv bf16 ----------------
// W_tt[out][in] = sum_o M2[out][o] * Rm[o][in]
//   out=(j,l2,n): j*64+l2*8+n ; in=(p,r,t): p*96+r*12+t
// grid (L, 2, 16): z-slice = 48 output rows; chain contraction redundantly
// recomputed per slice (trivial) so the 84 MB materialization gets 384 blocks.
__global__ void tt_prep_kernel(
    const float* __restrict__ qc0, const float* __restrict__ qc1, const float* __restrict__ qc2,
    const float* __restrict__ qc3, const float* __restrict__ qc4, const float* __restrict__ qc5,
    const float* __restrict__ vc0, const float* __restrict__ vc1, const float* __restrict__ vc2,
    const float* __restrict__ vc3, const float* __restrict__ vc4, const float* __restrict__ vc5,
    const float* __restrict__ Wq, const float* __restrict__ Wv,
    const int* __restrict__ e_idx, __bf16* __restrict__ wqkv) {
  const int l = blockIdx.x;
  const int pre = blockIdx.y;         // 0 = q, 1 = v
  const int z = blockIdx.z;           // 0..15 -> rows 48z..48z+47
  const int tid = threadIdx.x;
  const int e = e_idx[0];
  const float* c0 = (pre ? vc0 : qc0) + (size_t)(e*L_ + l)*96;   // [12][8]
  const float* c1 = (pre ? vc1 : qc1) + (size_t)(e*L_ + l)*512;  // [8][8][8]
  const float* c2 = (pre ? vc2 : qc2) + (size_t)(e*L_ + l)*512;
  const float* c3 = (pre ? vc3 : qc3) + (size_t)(e*L_ + l)*512;
  const float* c4 = (pre ? vc4 : qc4) + (size_t)(e*L_ + l)*512;
  const float* c5 = (pre ? vc5 : qc5) + (size_t)(e*L_ + l)*96;   // [8][12]
  __shared__ float M1[768];   // [j][l2][m]
  __shared__ float R2[768];   // [q][r][t]
  __shared__ float M2[6144];  // [out][o]
  __shared__ float Rm[6144];  // [o][in]
  for (int idx = tid; idx < 768; idx += 256) {
    int j = idx >> 6, rem = idx & 63, l2 = rem >> 3, m = rem & 7;
    float s = 0.f;
    for (int k = 0; k < 8; ++k) s += c0[j*8 + k] * c1[k*64 + l2*8 + m];
    M1[idx] = s;
    int qq = idx / 96, rem2 = idx % 96, rr = rem2 / 12, t = rem2 % 12;
    float s2 = 0.f;
    for (int si = 0; si < 8; ++si) s2 += c4[qq*64 + rr*8 + si] * c5[si*12 + t];
    R2[idx] = s2;
  }
  __syncthreads();
  for (int idx = tid; idx < 6144; idx += 256) {
    int o = idx & 7, n = (idx >> 3) & 7, jl = idx >> 6;
    float s = 0.f;
    for (int m = 0; m < 8; ++m) s += M1[jl*8 + m] * c2[m*64 + n*8 + o];
    M2[idx] = s;
    int o2 = idx / 768, inp = idx % 768, p = inp / 96, rt = inp % 96;
    float s2 = 0.f;
    for (int qq = 0; qq < 8; ++qq) s2 += c3[o2*64 + p*8 + qq] * R2[qq*96 + rt];
    Rm[idx] = s2;
  }
  __syncthreads();
  const float* Wbase = (pre ? Wv : Wq) + (size_t)l*D_*D_;
  __bf16* dst = wqkv + (size_t)l*2304*D_ + (pre ? (size_t)1536*D_ : 0);
  // 48 rows x 96 col-groups of 8; vectorized: 2x float4 Rm reads + bf16x8 store
  for (int g = tid; g < 48*96; g += 256) {
    const int outr = z*48 + (g / 96);
    const int inp0 = (g % 96) * 8;
    float m2r[8];
#pragma unroll
    for (int o = 0; o < 8; ++o) m2r[o] = M2[outr*8 + o];
    float acc[8];
#pragma unroll
    for (int u = 0; u < 8; ++u) acc[u] = 0.f;
#pragma unroll
    for (int o = 0; o < 8; ++o) {
      float4 r0 = *(const float4*)&Rm[o*768 + inp0];
      float4 r1 = *(const float4*)&Rm[o*768 + inp0 + 4];
      acc[0] += m2r[o]*r0.x; acc[1] += m2r[o]*r0.y;
      acc[2] += m2r[o]*r0.z; acc[3] += m2r[o]*r0.w;
      acc[4] += m2r[o]*r1.x; acc[5] += m2r[o]*r1.y;
      acc[6] += m2r[o]*r1.z; acc[7] += m2r[o]*r1.w;
    }
    const float* wb = Wbase + (size_t)outr*768 + inp0;
    float4 w0 = *(const float4*)wb;
    float4 w1 = *(const float4*)(wb + 4);
    __bf16 r[8];
    r[0] = f2bf(w0.x + 8.f*acc[0]); r[1] = f2bf(w0.y + 8.f*acc[1]);
    r[2] = f2bf(w0.z + 8.f*acc[2]); r[3] = f2bf(w0.w + 8.f*acc[3]);
    r[4] = f2bf(w1.x + 8.f*acc[4]); r[5] = f2bf(w1.y + 8.f*acc[5]);
    r[6] = f2bf(w1.z + 8.f*acc[6]); r[7] = f2bf(w1.w + 8.f*acc[7]);
    *(bf16x8*)(dst + (size_t)outr*768 + inp0) = *(bf16x8*)r;
  }
}

// ---------------- bf16 MFMA GEMM: C[M][Nw] = A[M][768] * Bw[Nw][768]^T + bias ----------------
template<bool OUTBF>
__global__ __launch_bounds__(256) void gemm_bt(
    const __bf16* __restrict__ A, const __bf16* __restrict__ Bw,
    const float* __restrict__ bq, const float* __restrict__ bk, const float* __restrict__ bvp,
    __bf16* __restrict__ outb, float* __restrict__ outf, int Nw) {
  const int K = D_;
  __shared__ __align__(16) __bf16 As[128*64];
  __shared__ __align__(16) __bf16 Bs[128*64];
  const int tid = threadIdx.x;
  const int w = tid >> 6, lane = tid & 63;
  const int quad = lane >> 4, l16 = lane & 15;
  const int wr = w >> 1, wc = w & 1;
  const size_t mblk = (size_t)blockIdx.y * 128;
  const size_t nblk = (size_t)blockIdx.x * 128;
  const __bf16* Ab = A + mblk * K;
  const __bf16* Bb = Bw + nblk * K;
  const int lrow = lane >> 3;        // 0..7
  const int scol = (lane & 7) * 8;   // element offset in K
  floatx4 acc[4][4];
#pragma unroll
  for (int i = 0; i < 4; ++i)
#pragma unroll
    for (int j = 0; j < 4; ++j) acc[i][j] = {0.f,0.f,0.f,0.f};

  for (int k0 = 0; k0 < K; k0 += 64) {
    __syncthreads();
#pragma unroll
    for (int i = 0; i < 4; ++i) {
      const int chunk = w*4 + i;           // wave-uniform
      const int row = chunk*8 + lrow;
      async16(Ab + (size_t)row*K + k0 + scol, &As[chunk*512]);
      async16(Bb + (size_t)row*K + k0 + scol, &Bs[chunk*512]);
    }
    __syncthreads();
#pragma unroll
    for (int kk = 0; kk < 64; kk += 32) {
      bf16x8 af[4], bfr[4];
#pragma unroll
      for (int i = 0; i < 4; ++i) af[i]  = *(const bf16x8*)&As[(wr*64 + i*16 + l16)*64 + kk + quad*8];
#pragma unroll
      for (int j = 0; j < 4; ++j) bfr[j] = *(const bf16x8*)&Bs[(wc*64 + j*16 + l16)*64 + kk + quad*8];
#pragma unroll
      for (int i = 0; i < 4; ++i)
#pragma unroll
        for (int j = 0; j < 4; ++j)
          acc[i][j] = __builtin_amdgcn_mfma_f32_16x16x32_bf16(af[i], bfr[j], acc[i][j], 0, 0, 0);
    }
  }
  const float* bias = bq;
  if (Nw == 2304) bias = (blockIdx.x < 6) ? bq : (blockIdx.x < 12 ? bk : bvp);
#pragma unroll
  for (int i = 0; i < 4; ++i) {
#pragma unroll
    for (int j = 0; j < 4; ++j) {
      const int ncol = (int)nblk + wc*64 + j*16 + l16;
      const float bval = bias[ncol % 768];
#pragma unroll
      for (int r = 0; r < 4; ++r) {
        const int mrow = (int)mblk + wr*64 + i*16 + quad*4 + r;
        float v = acc[i][j][r] + bval;
        if (OUTBF) outb[(size_t)mrow*Nw + ncol] = f2bf(v);
        else       outf[(size_t)mrow*Nw + ncol] = v;
      }
    }
  }
}

// ---------------- V transpose: qkv V-seg [b,s,h,d] -> vt [b,h,d,s] ----------------
__global__ void transpose_v_kernel(const __bf16* __restrict__ qkv, __bf16* __restrict__ vt) {
  __shared__ __bf16 tile[64*66];   // pad 66: conflict-free strided read
  const int tid = threadIdx.x;
  const int s0 = blockIdx.x * 64;
  const int h = blockIdx.y, b = blockIdx.z;
#pragma unroll
  for (int p = 0; p < 16; ++p) {
    int idx = p*256 + tid;
    int sl = idx >> 6, d = idx & 63;
    tile[sl*66 + d] = qkv[(size_t)(b*S_ + s0 + sl)*2304 + 1536 + h*64 + d];
  }
  __syncthreads();
#pragma unroll
  for (int p = 0; p < 16; ++p) {
    int idx = p*256 + tid;
    int d = idx >> 6, sl = idx & 63;
    vt[(size_t)((b*H_ + h)*64 + d)*S_ + s0 + sl] = tile[sl*66 + d];
  }
}

// ---------------- flash attention: per (b,h,64-row Q tile) ----------------
__global__ __launch_bounds__(256) void flash_kernel(const __bf16* __restrict__ qkv,
                                                    const __bf16* __restrict__ vt,
                                                    __bf16* __restrict__ ctx) {
  __shared__ __align__(16) __bf16 Qs[64*64];   // [q][d]
  __shared__ __align__(16) __bf16 Ks[64*64];   // [kv][d]
  __shared__ __align__(16) __bf16 Vts[64*64];  // [d][kv]
  __shared__ __align__(16) __bf16 Ps[64*64];   // [q][kv]
  const int tid = threadIdx.x;
  const int w = tid >> 6, lane = tid & 63;
  const int quad = lane >> 4, l16 = lane & 15;
  const int q0 = blockIdx.x * 64;
  const int h = blockIdx.y, b = blockIdx.z;
  const int lrow = lane >> 3;
  const int lcol = (lane & 7) * 8;

  // stage Q once (8 chunks of 1KB; wave w handles 2w, 2w+1)
#pragma unroll
  for (int i = 0; i < 2; ++i) {
    const int chunk = w*2 + i;
    const int row = chunk*8 + lrow;
    async16(qkv + (size_t)(b*S_ + q0 + row)*2304 + h*64 + lcol, &Qs[chunk*512]);
  }

  floatx4 acc_o[4];
#pragma unroll
  for (int j = 0; j < 4; ++j) acc_o[j] = {0.f,0.f,0.f,0.f};
  float m_prev[4], l_prev[4];
#pragma unroll
  for (int r = 0; r < 4; ++r) { m_prev[r] = -__builtin_inff(); l_prev[r] = 0.f; }

  for (int kt = 0; kt < 8; ++kt) {
    __syncthreads();
#pragma unroll
    for (int i = 0; i < 2; ++i) {
      const int chunk = w*2 + i;
      const int row = chunk*8 + lrow;
      async16(qkv + (size_t)(b*S_ + kt*64 + row)*2304 + 768 + h*64 + lcol, &Ks[chunk*512]);
      async16(vt + (size_t)((b*H_ + h)*64 + row)*S_ + kt*64 + lcol, &Vts[chunk*512]);
    }
    __syncthreads();
    // S = Q K^T (wave w owns rows w*16..w*16+15)
    floatx4 sacc[4];
#pragma unroll
    for (int j = 0; j < 4; ++j) sacc[j] = {0.f,0.f,0.f,0.f};
#pragma unroll
    for (int kk = 0; kk < 64; kk += 32) {
      bf16x8 aq = *(const bf16x8*)&Qs[(w*16 + l16)*64 + kk + quad*8];
#pragma unroll
      for (int j = 0; j < 4; ++j) {
        bf16x8 bk_ = *(const bf16x8*)&Ks[(j*16 + l16)*64 + kk + quad*8];
        sacc[j] = __builtin_amdgcn_mfma_f32_16x16x32_bf16(aq, bk_, sacc[j], 0, 0, 0);
      }
    }
    float sv[4][4];
#pragma unroll
    for (int j = 0; j < 4; ++j)
#pragma unroll
      for (int r = 0; r < 4; ++r) sv[j][r] = sacc[j][r] * 0.125f;
    float mnew[4], alpha[4], rsum[4];
#pragma unroll
    for (int r = 0; r < 4; ++r) {
      float mv = fmaxf(fmaxf(sv[0][r], sv[1][r]), fmaxf(sv[2][r], sv[3][r]));
#pragma unroll
      for (int off = 1; off < 16; off <<= 1) mv = fmaxf(mv, __shfl_xor(mv, off));
      float mn = fmaxf(m_prev[r], mv);
      mnew[r] = mn;
      alpha[r] = __expf(m_prev[r] - mn);
      rsum[r] = 0.f;
    }
#pragma unroll
    for (int j = 0; j < 4; ++j)
#pragma unroll
      for (int r = 0; r < 4; ++r) {
        float p = __expf(sv[j][r] - mnew[r]);
        rsum[r] += p;
        Ps[(w*16 + quad*4 + r)*64 + j*16 + l16] = f2bf(p);  // same-wave rows only
      }
#pragma unroll
    for (int r = 0; r < 4; ++r) {
      float s = rsum[r];
#pragma unroll
      for (int off = 1; off < 16; off <<= 1) s += __shfl_xor(s, off);
      l_prev[r] = l_prev[r]*alpha[r] + s;
      m_prev[r] = mnew[r];
    }
#pragma unroll
    for (int j = 0; j < 4; ++j)
#pragma unroll
      for (int r = 0; r < 4; ++r) acc_o[j][r] = acc_o[j][r] * alpha[r];
    // O += P V   (DS ops are in-order per wave: P write->read safe without barrier)
#pragma unroll
    for (int kk = 0; kk < 64; kk += 32) {
      bf16x8 ap = *(const bf16x8*)&Ps[(w*16 + l16)*64 + kk + quad*8];
#pragma unroll
      for (int j = 0; j < 4; ++j) {
        bf16x8 bv_ = *(const bf16x8*)&Vts[(j*16 + l16)*64 + kk + quad*8];
        acc_o[j] = __builtin_amdgcn_mfma_f32_16x16x32_bf16(ap, bv_, acc_o[j], 0, 0, 0);
      }
    }
  }
#pragma unroll
  for (int j = 0; j < 4; ++j) {
    const int d = j*16 + l16;
#pragma unroll
    for (int r = 0; r < 4; ++r) {
      const int q = q0 + w*16 + quad*4 + r;
      float v = acc_o[j][r] / l_prev[r];
      ctx[(size_t)(b*S_ + q)*D_ + h*64 + d] = f2bf(v);
    }
  }
}

// ---------------- residual + LayerNorm (fp32), writes fp32 master + bf16 copy ----------------
__global__ __launch_bounds__(256) void ln_kernel(const float* __restrict__ resid,
                                                 const float* __restrict__ proj,
                                                 const float* __restrict__ gamma,
                                                 const float* __restrict__ beta,
                                                 float* __restrict__ xout,
                                                 __bf16* __restrict__ xbf) {
  const int row = blockIdx.x;
  const int tid = threadIdx.x;
  const int w = tid >> 6, lane = tid & 63;
  __shared__ float red[4];
  float v[3]; int dd[3];
#pragma unroll
  for (int i = 0; i < 3; ++i) {
    int d = tid + i*256; dd[i] = d;
    v[i] = resid[(size_t)row*D_ + d] + proj[(size_t)row*D_ + d];
  }
  float s = v[0] + v[1] + v[2];
#pragma unroll
  for (int off = 32; off; off >>= 1) s += __shfl_xor(s, off);
  if (lane == 0) red[w] = s;
  __syncthreads();
  float mu = (red[0]+red[1]+red[2]+red[3]) * (1.f/768.f);
  __syncthreads();
  float q = 0.f;
#pragma unroll
  for (int i = 0; i < 3; ++i) { float d = v[i]-mu; q += d*d; }
#pragma unroll
  for (int off = 32; off; off >>= 1) q += __shfl_xor(q, off);
  if (lane == 0) red[w] = q;
  __syncthreads();
  float var = (red[0]+red[1]+red[2]+red[3]) * (1.f/768.f);
  float rs = rsqrtf(var + 1e-12f);
#pragma unroll
  for (int i = 0; i < 3; ++i) {
    float o = (v[i]-mu)*rs*gamma[dd[i]] + beta[dd[i]];
    xout[(size_t)row*D_ + dd[i]] = o;
    xbf[(size_t)row*D_ + dd[i]] = f2bf(o);
  }
}

extern "C" void kernel_launch(void* const* d_in, const int* in_sizes, int n_in,
                              void* d_out, int out_size, void* d_ws, size_t ws_size,
                              hipStream_t stream) {
  const float* hidden = (const float*)d_in[0];
  const float* router = (const float*)d_in[1];
  const float* qc[6]; const float* vc[6];
  for (int i = 0; i < 6; ++i) qc[i] = (const float*)d_in[2+i];
  for (int i = 0; i < 6; ++i) vc[i] = (const float*)d_in[8+i];
  const float* Wq = (const float*)d_in[14];
  const float* Wk = (const float*)d_in[15];
  const float* Wv = (const float*)d_in[16];
  const float* Wo = (const float*)d_in[17];
  const float* bq = (const float*)d_in[18];
  const float* bk = (const float*)d_in[19];
  const float* bv = (const float*)d_in[20];
  const float* bo = (const float*)d_in[21];
  const float* lns = (const float*)d_in[22];
  const float* lnb = (const float*)d_in[23];
  float* out = (float*)d_out;

  char* ws = (char*)d_ws;
  size_t off = 0;
  auto alloc = [&](size_t bytes) -> void* {
    off = (off + 255) & ~(size_t)255;
    void* p = ws + off; off += bytes; return p;
  };
  int*    e_idx = (int*)   alloc(4);
  __bf16* xbf   = (__bf16*)alloc((size_t)BS_*D_*2);
  __bf16* qkv   = (__bf16*)alloc((size_t)BS_*2304*2);
  __bf16* vt    = (__bf16*)alloc((size_t)B_*H_*64*S_*2);
  __bf16* ctx   = (__bf16*)alloc((size_t)BS_*D_*2);
  float*  proj  = (float*) alloc((size_t)BS_*D_*4);
  __bf16* wqkv  = (__bf16*)alloc((size_t)L_*2304*D_*2);
  __bf16* wobf  = (__bf16*)alloc((size_t)L_*D_*D_*2);
  (void)ws_size; (void)in_sizes; (void)n_in; (void)out_size;

  routing_kernel<<<1, 256, 0, stream>>>(hidden, router, e_idx);
  convert_bf16_kernel<<<(BS_*D_)/2048, 256, 0, stream>>>(hidden, xbf);
  tt_prep_kernel<<<dim3(L_, 2, 16), 256, 0, stream>>>(qc[0],qc[1],qc[2],qc[3],qc[4],qc[5],
                                                      vc[0],vc[1],vc[2],vc[3],vc[4],vc[5],
                                                      Wq, Wv, e_idx, wqkv);
  convert_wk_kernel<<<(L_*D_*D_)/2048, 256, 0, stream>>>(Wk, wqkv);
  convert_bf16_kernel<<<(L_*D_*D_)/2048, 256, 0, stream>>>(Wo, wobf);

  for (int l = 0; l < L_; ++l) {
    gemm_bt<true><<<dim3(18,128), 256, 0, stream>>>(xbf, wqkv + (size_t)l*2304*D_,
        bq + l*D_, bk + l*D_, bv + l*D_, qkv, nullptr, 2304);
    transpose_v_kernel<<<dim3(8,H_,B_), 256, 0, stream>>>(qkv, vt);
    flash_kernel<<<dim3(8,H_,B_), 256, 0, stream>>>(qkv, vt, ctx);
    gemm_bt<false><<<dim3(6,128), 256, 0, stream>>>(ctx, wobf + (size_t)l*D_*D_,
        bo + l*D_, nullptr, nullptr, nullptr, proj, 768);
    ln_kernel<<<BS_, 256, 0, stream>>>(l == 0 ? hidden : out, proj,
        lns + l*D_, lnb + l*D_, out, xbf);
  }
}

// Round 3
// 3289.372 us; speedup vs baseline: 1.3414x; 1.1809x over previous
//
#include <hip/hip_runtime.h>
#include <hip/hip_bf16.h>
#include <stdint.h>

#define E_ 8
#define L_ 12
#define D_ 768
#define H_ 12
#define S_ 512
#define B_ 32
#define BS_ (B_*S_)   // 16384

typedef __attribute__((ext_vector_type(4))) float floatx4;
typedef __attribute__((ext_vector_type(8))) __bf16 bf16x8;
typedef __attribute__((ext_vector_type(4))) __bf16 bf16x4;

__device__ __forceinline__ __bf16 f2bf(float f) {
  unsigned u = __builtin_bit_cast(unsigned, f);
  u += 0x7fffu + ((u >> 16) & 1u);           // RNE
  unsigned short h = (unsigned short)(u >> 16);
  return __builtin_bit_cast(__bf16, h);
}

__device__ __forceinline__ float fexp2(float x) {
#if __has_builtin(__builtin_amdgcn_exp2f)
  return __builtin_amdgcn_exp2f(x);
#else
  return exp2f(x);
#endif
}

__device__ __forceinline__ void async16(const void* g, void* l) {
  __builtin_amdgcn_global_load_lds((__attribute__((address_space(1))) void*)g,
                                   (__attribute__((address_space(3))) void*)l,
                                   16, 0, 0);
}

// ---------------- routing: argmax logits of sample B-1 ----------------
__global__ void routing_kernel(const float* __restrict__ hidden,
                               const float* __restrict__ rw,
                               int* __restrict__ e_out) {
  __shared__ float pooled[D_];
  __shared__ float logits[E_];
  int tid = threadIdx.x;
  for (int d = tid; d < D_; d += 256) {
    float s = 0.f;
    const float* p = hidden + (size_t)(B_-1)*S_*D_ + d;
    for (int ss = 0; ss < S_; ++ss) s += p[(size_t)ss*D_];
    pooled[d] = s;  // positive scale factor irrelevant for argmax
  }
  __syncthreads();
  if (tid < E_) {
    float s = 0.f;
    for (int d = 0; d < D_; ++d) s += pooled[d] * rw[d*E_ + tid];
    logits[tid] = s;
  }
  __syncthreads();
  if (tid == 0) {
    int best = 0; float bvv = logits[0];
    for (int e = 1; e < E_; ++e) if (logits[e] > bvv) { bvv = logits[e]; best = e; }
    e_out[0] = best;
  }
}

// ---------------- fp32 -> bf16 convert (n multiple of 2048) ----------------
__global__ void convert_bf16_kernel(const float* __restrict__ src, __bf16* __restrict__ dst) {
  size_t i = ((size_t)blockIdx.x*256 + threadIdx.x)*8;
  __bf16 r[8];
#pragma unroll
  for (int j = 0; j < 8; ++j) r[j] = f2bf(src[i+j]);
  *(bf16x8*)(dst + i) = *(bf16x8*)r;
}

// Wk [L][768][768] fp32 -> rows 768..1535 of wqkv [L][2304][768] bf16
__global__ void convert_wk_kernel(const float* __restrict__ wk, __bf16* __restrict__ wqkv) {
  size_t i = ((size_t)blockIdx.x*256 + threadIdx.x)*8;
  int l = (int)(i / (D_*D_));
  int rem = (int)(i % (D_*D_));
  int n = rem / D_, k = rem % D_;
  __bf16 r[8];
#pragma unroll
  for (int j = 0; j < 8; ++j) r[j] = f2bf(wk[i+j]);
  *(bf16x8*)(wqkv + (size_t)l*2304*D_ + (size_t)(768+n)*D_ + k) = *(bf16x8*)r;
}

// ---------------- TT adapter build: Wq_a / Wv_a -> wqkv bf16 ----------------
__global__ void tt_prep_kernel(
    const float* __restrict__ qc0, const float* __restrict__ qc1, const float* __restrict__ qc2,
    const float* __restrict__ qc3, const float* __restrict__ qc4, const float* __restrict__ qc5,
    const float* __restrict__ vc0, const float* __restrict__ vc1, const float* __restrict__ vc2,
    const float* __restrict__ vc3, const float* __restrict__ vc4, const float* __restrict__ vc5,
    const float* __restrict__ Wq, const float* __restrict__ Wv,
    const int* __restrict__ e_idx, __bf16* __restrict__ wqkv) {
  const int l = blockIdx.x;
  const int pre = blockIdx.y;         // 0 = q, 1 = v
  const int z = blockIdx.z;           // 0..15 -> rows 48z..48z+47
  const int tid = threadIdx.x;
  const int e = e_idx[0];
  const float* c0 = (pre ? vc0 : qc0) + (size_t)(e*L_ + l)*96;   // [12][8]
  const float* c1 = (pre ? vc1 : qc1) + (size_t)(e*L_ + l)*512;  // [8][8][8]
  const float* c2 = (pre ? vc2 : qc2) + (size_t)(e*L_ + l)*512;
  const float* c3 = (pre ? vc3 : qc3) + (size_t)(e*L_ + l)*512;
  const float* c4 = (pre ? vc4 : qc4) + (size_t)(e*L_ + l)*512;
  const float* c5 = (pre ? vc5 : qc5) + (size_t)(e*L_ + l)*96;   // [8][12]
  __shared__ float M1[768];   // [j][l2][m]
  __shared__ float R2[768];   // [q][r][t]
  __shared__ float M2[6144];  // [out][o]
  __shared__ float Rm[6144];  // [o][in]
  for (int idx = tid; idx < 768; idx += 256) {
    int j = idx >> 6, rem = idx & 63, l2 = rem >> 3, m = rem & 7;
    float s = 0.f;
    for (int k = 0; k < 8; ++k) s += c0[j*8 + k] * c1[k*64 + l2*8 + m];
    M1[idx] = s;
    int qq = idx / 96, rem2 = idx % 96, rr = rem2 / 12, t = rem2 % 12;
    float s2 = 0.f;
    for (int si = 0; si < 8; ++si) s2 += c4[qq*64 + rr*8 + si] * c5[si*12 + t];
    R2[idx] = s2;
  }
  __syncthreads();
  for (int idx = tid; idx < 6144; idx += 256) {
    int o = idx & 7, n = (idx >> 3) & 7, jl = idx >> 6;
    float s = 0.f;
    for (int m = 0; m < 8; ++m) s += M1[jl*8 + m] * c2[m*64 + n*8 + o];
    M2[idx] = s;
    int o2 = idx / 768, inp = idx % 768, p = inp / 96, rt = inp % 96;
    float s2 = 0.f;
    for (int qq = 0; qq < 8; ++qq) s2 += c3[o2*64 + p*8 + qq] * R2[qq*96 + rt];
    Rm[idx] = s2;
  }
  __syncthreads();
  const float* Wbase = (pre ? Wv : Wq) + (size_t)l*D_*D_;
  __bf16* dst = wqkv + (size_t)l*2304*D_ + (pre ? (size_t)1536*D_ : 0);
  for (int g = tid; g < 48*96; g += 256) {
    const int outr = z*48 + (g / 96);
    const int inp0 = (g % 96) * 8;
    float m2r[8];
#pragma unroll
    for (int o = 0; o < 8; ++o) m2r[o] = M2[outr*8 + o];
    float acc[8];
#pragma unroll
    for (int u = 0; u < 8; ++u) acc[u] = 0.f;
#pragma unroll
    for (int o = 0; o < 8; ++o) {
      float4 r0 = *(const float4*)&Rm[o*768 + inp0];
      float4 r1 = *(const float4*)&Rm[o*768 + inp0 + 4];
      acc[0] += m2r[o]*r0.x; acc[1] += m2r[o]*r0.y;
      acc[2] += m2r[o]*r0.z; acc[3] += m2r[o]*r0.w;
      acc[4] += m2r[o]*r1.x; acc[5] += m2r[o]*r1.y;
      acc[6] += m2r[o]*r1.z; acc[7] += m2r[o]*r1.w;
    }
    const float* wb = Wbase + (size_t)outr*768 + inp0;
    float4 w0 = *(const float4*)wb;
    float4 w1 = *(const float4*)(wb + 4);
    __bf16 r[8];
    r[0] = f2bf(w0.x + 8.f*acc[0]); r[1] = f2bf(w0.y + 8.f*acc[1]);
    r[2] = f2bf(w0.z + 8.f*acc[2]); r[3] = f2bf(w0.w + 8.f*acc[3]);
    r[4] = f2bf(w1.x + 8.f*acc[4]); r[5] = f2bf(w1.y + 8.f*acc[5]);
    r[6] = f2bf(w1.z + 8.f*acc[6]); r[7] = f2bf(w1.w + 8.f*acc[7]);
    *(bf16x8*)(dst + (size_t)outr*768 + inp0) = *(bf16x8*)r;
  }
}

// ---------------- bf16 MFMA GEMM: C[M][Nw] = A[M][768] * Bw[Nw][768]^T + bias ----------------
template<bool OUTBF>
__global__ __launch_bounds__(256) void gemm_bt(
    const __bf16* __restrict__ A, const __bf16* __restrict__ Bw,
    const float* __restrict__ bq, const float* __restrict__ bk, const float* __restrict__ bvp,
    __bf16* __restrict__ outb, float* __restrict__ outf, int Nw) {
  const int K = D_;
  __shared__ __align__(16) __bf16 As[128*64];
  __shared__ __align__(16) __bf16 Bs[128*64];
  const int tid = threadIdx.x;
  const int w = tid >> 6, lane = tid & 63;
  const int quad = lane >> 4, l16 = lane & 15;
  const int wr = w >> 1, wc = w & 1;
  const size_t mblk = (size_t)blockIdx.y * 128;
  const size_t nblk = (size_t)blockIdx.x * 128;
  const __bf16* Ab = A + mblk * K;
  const __bf16* Bb = Bw + nblk * K;
  const int lrow = lane >> 3;        // 0..7
  const int scol = (lane & 7) * 8;   // element offset in K
  floatx4 acc[4][4];
#pragma unroll
  for (int i = 0; i < 4; ++i)
#pragma unroll
    for (int j = 0; j < 4; ++j) acc[i][j] = {0.f,0.f,0.f,0.f};

  for (int k0 = 0; k0 < K; k0 += 64) {
    __syncthreads();
#pragma unroll
    for (int i = 0; i < 4; ++i) {
      const int chunk = w*4 + i;           // wave-uniform
      const int row = chunk*8 + lrow;
      async16(Ab + (size_t)row*K + k0 + scol, &As[chunk*512]);
      async16(Bb + (size_t)row*K + k0 + scol, &Bs[chunk*512]);
    }
    __syncthreads();
#pragma unroll
    for (int kk = 0; kk < 64; kk += 32) {
      bf16x8 af[4], bfr[4];
#pragma unroll
      for (int i = 0; i < 4; ++i) af[i]  = *(const bf16x8*)&As[(wr*64 + i*16 + l16)*64 + kk + quad*8];
#pragma unroll
      for (int j = 0; j < 4; ++j) bfr[j] = *(const bf16x8*)&Bs[(wc*64 + j*16 + l16)*64 + kk + quad*8];
#pragma unroll
      for (int i = 0; i < 4; ++i)
#pragma unroll
        for (int j = 0; j < 4; ++j)
          acc[i][j] = __builtin_amdgcn_mfma_f32_16x16x32_bf16(af[i], bfr[j], acc[i][j], 0, 0, 0);
    }
  }
  const float* bias = bq;
  if (Nw == 2304) bias = (blockIdx.x < 6) ? bq : (blockIdx.x < 12 ? bk : bvp);
#pragma unroll
  for (int i = 0; i < 4; ++i) {
#pragma unroll
    for (int j = 0; j < 4; ++j) {
      const int ncol = (int)nblk + wc*64 + j*16 + l16;
      const float bval = bias[ncol % 768];
#pragma unroll
      for (int r = 0; r < 4; ++r) {
        const int mrow = (int)mblk + wr*64 + i*16 + quad*4 + r;
        float v = acc[i][j][r] + bval;
        if (OUTBF) outb[(size_t)mrow*Nw + ncol] = f2bf(v);
        else       outf[(size_t)mrow*Nw + ncol] = v;
      }
    }
  }
}

// ---------------- V transpose: qkv V-seg [b,s,h,d] -> vt [b,h,d,s] ----------------
__global__ void transpose_v_kernel(const __bf16* __restrict__ qkv, __bf16* __restrict__ vt) {
  __shared__ __bf16 tile[64*66];   // pad 66: conflict-free strided read
  const int tid = threadIdx.x;
  const int s0 = blockIdx.x * 64;
  const int h = blockIdx.y, b = blockIdx.z;
#pragma unroll
  for (int p = 0; p < 16; ++p) {
    int idx = p*256 + tid;
    int sl = idx >> 6, d = idx & 63;
    tile[sl*66 + d] = qkv[(size_t)(b*S_ + s0 + sl)*2304 + 1536 + h*64 + d];
  }
  __syncthreads();
#pragma unroll
  for (int p = 0; p < 16; ++p) {
    int idx = p*256 + tid;
    int d = idx >> 6, sl = idx & 63;
    vt[(size_t)((b*H_ + h)*64 + d)*S_ + s0 + sl] = tile[sl*66 + d];
  }
}

// ---------------- flash attention v2: S^T-mfma, padded LDS, XCD swizzle ----------------
// 1-D grid of 3072: n&7 selects XCD-slot; bh = (n>>6)*8 + (n&7); qtile = (n>>3)&7.
// All 8 q-tiles of a (b,h) run on the same XCD within 64 consecutive blocks.
#define PSTR 72   // padded LDS row stride (bf16): 144 B -> bank-even b128 access
__global__ __launch_bounds__(256) void flash_kernel(const __bf16* __restrict__ qkv,
                                                    const __bf16* __restrict__ vt,
                                                    __bf16* __restrict__ ctx) {
  __shared__ __align__(16) __bf16 Qs[64*PSTR];    // [q][d]
  __shared__ __align__(16) __bf16 Ks[64*PSTR];    // [kv][d]
  __shared__ __align__(16) __bf16 Vts[64*PSTR];   // [d][kv]
  __shared__ __align__(16) __bf16 Ps[64*PSTR];    // [q][kv], wave w owns rows w*16..+15
  const int tid = threadIdx.x;
  const int w = tid >> 6, lane = tid & 63;
  const int quad = lane >> 4, l16 = lane & 15;
  const int n = blockIdx.x;
  const int bh = (n >> 6)*8 + (n & 7);
  const int q0 = ((n >> 3) & 7) * 64;
  const int b = bh / H_, h = bh % H_;
  const float SCL = 0.125f * 1.44269504f;  // 1/sqrt(64) * log2(e)

  // stage Q once: 512 slots (row 0..63, seg 0..7), 2 per thread
  {
#pragma unroll
    for (int it = 0; it < 2; ++it) {
      int slot = it*256 + tid, row = slot >> 3, seg = slot & 7;
      bf16x8 v = *(const bf16x8*)(qkv + (size_t)(b*S_ + q0 + row)*2304 + h*64 + seg*8);
      *(bf16x8*)&Qs[row*PSTR + seg*8] = v;
    }
  }

  floatx4 acc_o[4];   // C[m=q_local=quad*4+r][n=d=jd*16+l16]
#pragma unroll
  for (int jd = 0; jd < 4; ++jd) acc_o[jd] = {0.f,0.f,0.f,0.f};
  float m_prev = -__builtin_inff();   // per-lane q = w*16 + l16 (log2 domain)
  float l_part = 0.f;                 // per-quad partial of the softmax denom

  for (int kt = 0; kt < 8; ++kt) {
    __syncthreads();
    // stage K and V^T tiles (each 512 slots, 2 per thread per tensor)
#pragma unroll
    for (int it = 0; it < 2; ++it) {
      int slot = it*256 + tid, row = slot >> 3, seg = slot & 7;
      bf16x8 kvv = *(const bf16x8*)(qkv + (size_t)(b*S_ + kt*64 + row)*2304 + 768 + h*64 + seg*8);
      bf16x8 vtv = *(const bf16x8*)(vt + (size_t)(bh*64 + row)*S_ + kt*64 + seg*8);
      *(bf16x8*)&Ks[row*PSTR + seg*8] = kvv;
      *(bf16x8*)&Vts[row*PSTR + seg*8] = vtv;
    }
    __syncthreads();
    // S^T tile: mfma(A=K, B=Q) -> C[m=kv=i*16+quad*4+r][n=q=w*16+l16]
    floatx4 sacc[4];
#pragma unroll
    for (int i = 0; i < 4; ++i) sacc[i] = {0.f,0.f,0.f,0.f};
#pragma unroll
    for (int kk = 0; kk < 64; kk += 32) {
      bf16x8 bq_ = *(const bf16x8*)&Qs[(w*16 + l16)*PSTR + kk + quad*8];
#pragma unroll
      for (int i = 0; i < 4; ++i) {
        bf16x8 ak = *(const bf16x8*)&Ks[(i*16 + l16)*PSTR + kk + quad*8];
        sacc[i] = __builtin_amdgcn_mfma_f32_16x16x32_bf16(ak, bq_, sacc[i], 0, 0, 0);
      }
    }
    float sv[4][4];
#pragma unroll
    for (int i = 0; i < 4; ++i)
#pragma unroll
      for (int r = 0; r < 4; ++r) sv[i][r] = sacc[i][r] * SCL;
    // in-thread max over the 16 kv values this lane holds for its q-column
    float mloc = sv[0][0];
#pragma unroll
    for (int i = 0; i < 4; ++i)
#pragma unroll
      for (int r = 0; r < 4; ++r) mloc = fmaxf(mloc, sv[i][r]);
    mloc = fmaxf(mloc, __shfl_xor(mloc, 16));
    mloc = fmaxf(mloc, __shfl_xor(mloc, 32));
    float mnew = fmaxf(m_prev, mloc);
    float alpha = fexp2(m_prev - mnew);
    m_prev = mnew;
    float rsum = 0.f;
#pragma unroll
    for (int i = 0; i < 4; ++i) {
      __bf16 pr[4];
#pragma unroll
      for (int r = 0; r < 4; ++r) {
        float p = fexp2(sv[i][r] - mnew);
        rsum += p;
        pr[r] = f2bf(p);
      }
      *(bf16x4*)&Ps[(w*16 + l16)*PSTR + i*16 + quad*4] = *(bf16x4*)pr;  // b64, bank-even
    }
    l_part = l_part*alpha + rsum;    // per-quad partial; alpha uniform across quads
    // broadcast alpha into acc layout: need alpha of q_local = quad*4+r
    float ab[4];
#pragma unroll
    for (int r = 0; r < 4; ++r) ab[r] = __shfl(alpha, quad*4 + r);
#pragma unroll
    for (int jd = 0; jd < 4; ++jd)
#pragma unroll
      for (int r = 0; r < 4; ++r) acc_o[jd][r] *= ab[r];
    // O += P V : mfma(A=Ps rows, B=Vts rows); same-wave ds write->read is in-order
#pragma unroll
    for (int kk = 0; kk < 64; kk += 32) {
      bf16x8 ap = *(const bf16x8*)&Ps[(w*16 + l16)*PSTR + kk + quad*8];
#pragma unroll
      for (int jd = 0; jd < 4; ++jd) {
        bf16x8 bv_ = *(const bf16x8*)&Vts[(jd*16 + l16)*PSTR + kk + quad*8];
        acc_o[jd] = __builtin_amdgcn_mfma_f32_16x16x32_bf16(ap, bv_, acc_o[jd], 0, 0, 0);
      }
    }
  }
  // final denom: reduce per-quad partials, broadcast into acc layout
  float l_tot = l_part;
  l_tot += __shfl_xor(l_tot, 16);
  l_tot += __shfl_xor(l_tot, 32);
  float lb[4];
#pragma unroll
  for (int r = 0; r < 4; ++r) lb[r] = __shfl(l_tot, quad*4 + r);
#pragma unroll
  for (int jd = 0; jd < 4; ++jd) {
    const int d = jd*16 + l16;
#pragma unroll
    for (int r = 0; r < 4; ++r) {
      const int q = q0 + w*16 + quad*4 + r;
      ctx[(size_t)(b*S_ + q)*D_ + h*64 + d] = f2bf(acc_o[jd][r] / lb[r]);
    }
  }
}

// ---------------- residual + LayerNorm (fp32), writes fp32 master + bf16 copy ----------------
__global__ __launch_bounds__(256) void ln_kernel(const float* __restrict__ resid,
                                                 const float* __restrict__ proj,
                                                 const float* __restrict__ gamma,
                                                 const float* __restrict__ beta,
                                                 float* __restrict__ xout,
                                                 __bf16* __restrict__ xbf) {
  const int row = blockIdx.x;
  const int tid = threadIdx.x;
  const int w = tid >> 6, lane = tid & 63;
  __shared__ float red[4];
  float v[3]; int dd[3];
#pragma unroll
  for (int i = 0; i < 3; ++i) {
    int d = tid + i*256; dd[i] = d;
    v[i] = resid[(size_t)row*D_ + d] + proj[(size_t)row*D_ + d];
  }
  float s = v[0] + v[1] + v[2];
#pragma unroll
  for (int off = 32; off; off >>= 1) s += __shfl_xor(s, off);
  if (lane == 0) red[w] = s;
  __syncthreads();
  float mu = (red[0]+red[1]+red[2]+red[3]) * (1.f/768.f);
  __syncthreads();
  float q = 0.f;
#pragma unroll
  for (int i = 0; i < 3; ++i) { float d = v[i]-mu; q += d*d; }
#pragma unroll
  for (int off = 32; off; off >>= 1) q += __shfl_xor(q, off);
  if (lane == 0) red[w] = q;
  __syncthreads();
  float var = (red[0]+red[1]+red[2]+red[3]) * (1.f/768.f);
  float rs = rsqrtf(var + 1e-12f);
#pragma unroll
  for (int i = 0; i < 3; ++i) {
    float o = (v[i]-mu)*rs*gamma[dd[i]] + beta[dd[i]];
    xout[(size_t)row*D_ + dd[i]] = o;
    xbf[(size_t)row*D_ + dd[i]] = f2bf(o);
  }
}

extern "C" void kernel_launch(void* const* d_in, const int* in_sizes, int n_in,
                              void* d_out, int out_size, void* d_ws, size_t ws_size,
                              hipStream_t stream) {
  const float* hidden = (const float*)d_in[0];
  const float* router = (const float*)d_in[1];
  const float* qc[6]; const float* vc[6];
  for (int i = 0; i < 6; ++i) qc[i] = (const float*)d_in[2+i];
  for (int i = 0; i < 6; ++i) vc[i] = (const float*)d_in[8+i];
  const float* Wq = (const float*)d_in[14];
  const float* Wk = (const float*)d_in[15];
  const float* Wv = (const float*)d_in[16];
  const float* Wo = (const float*)d_in[17];
  const float* bq = (const float*)d_in[18];
  const float* bk = (const float*)d_in[19];
  const float* bv = (const float*)d_in[20];
  const float* bo = (const float*)d_in[21];
  const float* lns = (const float*)d_in[22];
  const float* lnb = (const float*)d_in[23];
  float* out = (float*)d_out;

  char* ws = (char*)d_ws;
  size_t off = 0;
  auto alloc = [&](size_t bytes) -> void* {
    off = (off + 255) & ~(size_t)255;
    void* p = ws + off; off += bytes; return p;
  };
  int*    e_idx = (int*)   alloc(4);
  __bf16* xbf   = (__bf16*)alloc((size_t)BS_*D_*2);
  __bf16* qkv   = (__bf16*)alloc((size_t)BS_*2304*2);
  __bf16* vt    = (__bf16*)alloc((size_t)B_*H_*64*S_*2);
  __bf16* ctx   = (__bf16*)alloc((size_t)BS_*D_*2);
  float*  proj  = (float*) alloc((size_t)BS_*D_*4);
  __bf16* wqkv  = (__bf16*)alloc((size_t)L_*2304*D_*2);
  __bf16* wobf  = (__bf16*)alloc((size_t)L_*D_*D_*2);
  (void)ws_size; (void)in_sizes; (void)n_in; (void)out_size;

  routing_kernel<<<1, 256, 0, stream>>>(hidden, router, e_idx);
  convert_bf16_kernel<<<(BS_*D_)/2048, 256, 0, stream>>>(hidden, xbf);
  tt_prep_kernel<<<dim3(L_, 2, 16), 256, 0, stream>>>(qc[0],qc[1],qc[2],qc[3],qc[4],qc[5],
                                                      vc[0],vc[1],vc[2],vc[3],vc[4],vc[5],
                                                      Wq, Wv, e_idx, wqkv);
  convert_wk_kernel<<<(L_*D_*D_)/2048, 256, 0, stream>>>(Wk, wqkv);
  convert_bf16_kernel<<<(L_*D_*D_)/2048, 256, 0, stream>>>(Wo, wobf);

  for (int l = 0; l < L_; ++l) {
    gemm_bt<true><<<dim3(18,128), 256, 0, stream>>>(xbf, wqkv + (size_t)l*2304*D_,
        bq + l*D_, bk + l*D_, bv + l*D_, qkv, nullptr, 2304);
    transpose_v_kernel<<<dim3(8,H_,B_), 256, 0, stream>>>(qkv, vt);
    flash_kernel<<<3072, 256, 0, stream>>>(qkv, vt, ctx);
    gemm_bt<false><<<dim3(6,128), 256, 0, stream>>>(ctx, wobf + (size_t)l*D_*D_,
        bo + l*D_, nullptr, nullptr, nullptr, proj, 768);
    ln_kernel<<<BS_, 256, 0, stream>>>(l == 0 ? hidden : out, proj,
        lns + l*D_, lnb + l*D_, out, xbf);
  }
}

// Round 4
// 3116.895 us; speedup vs baseline: 1.4156x; 1.0553x over previous
//
#include <hip/hip_runtime.h>
#include <hip/hip_bf16.h>
#include <stdint.h>

#define E_ 8
#define L_ 12
#define D_ 768
#define H_ 12
#define S_ 512
#define B_ 32
#define BS_ (B_*S_)   // 16384

typedef __attribute__((ext_vector_type(4))) float floatx4;
typedef __attribute__((ext_vector_type(8))) __bf16 bf16x8;
typedef __attribute__((ext_vector_type(4))) __bf16 bf16x4;

__device__ __forceinline__ __bf16 f2bf(float f) {
  unsigned u = __builtin_bit_cast(unsigned, f);
  u += 0x7fffu + ((u >> 16) & 1u);           // RNE
  unsigned short h = (unsigned short)(u >> 16);
  return __builtin_bit_cast(__bf16, h);
}

__device__ __forceinline__ float fexp2(float x) {
#if __has_builtin(__builtin_amdgcn_exp2f)
  return __builtin_amdgcn_exp2f(x);
#else
  return exp2f(x);
#endif
}

__device__ __forceinline__ void async16(const void* g, void* l) {
  __builtin_amdgcn_global_load_lds((__attribute__((address_space(1))) void*)g,
                                   (__attribute__((address_space(3))) void*)l,
                                   16, 0, 0);
}

// ---------------- routing stage 1: 64 blocks x 8 rows, coalesced partial sums ----------------
__global__ void routing_pool_kernel(const float* __restrict__ hidden,
                                    float* __restrict__ partial) {
  const int blk = blockIdx.x;    // 0..63
  const int tid = threadIdx.x;
  const float* base = hidden + (size_t)(B_-1)*S_*D_ + (size_t)blk*8*D_;
  float acc[3] = {0.f, 0.f, 0.f};
  for (int s = 0; s < 8; ++s) {
#pragma unroll
    for (int i = 0; i < 3; ++i)
      acc[i] += base[(size_t)s*D_ + tid + i*256];
  }
#pragma unroll
  for (int i = 0; i < 3; ++i) partial[(size_t)blk*D_ + tid + i*256] = acc[i];
}

// ---------------- routing stage 2: reduce partials, logits, argmax ----------------
__global__ void routing_finish_kernel(const float* __restrict__ partial,
                                      const float* __restrict__ rw,
                                      int* __restrict__ e_out) {
  __shared__ float pooled[D_];
  __shared__ float logits[E_];
  int tid = threadIdx.x;
#pragma unroll
  for (int i = 0; i < 3; ++i) {
    int d = tid + i*256;
    float s = 0.f;
    for (int blk = 0; blk < 64; ++blk) s += partial[(size_t)blk*D_ + d];
    pooled[d] = s;  // positive scale factor irrelevant for argmax
  }
  __syncthreads();
  if (tid < E_) {
    float s = 0.f;
    for (int d = 0; d < D_; ++d) s += pooled[d] * rw[d*E_ + tid];
    logits[tid] = s;
  }
  __syncthreads();
  if (tid == 0) {
    int best = 0; float bvv = logits[0];
    for (int e = 1; e < E_; ++e) if (logits[e] > bvv) { bvv = logits[e]; best = e; }
    e_out[0] = best;
  }
}

// ---------------- fp32 -> bf16 convert (n multiple of 2048) ----------------
__global__ void convert_bf16_kernel(const float* __restrict__ src, __bf16* __restrict__ dst) {
  size_t i = ((size_t)blockIdx.x*256 + threadIdx.x)*8;
  __bf16 r[8];
#pragma unroll
  for (int j = 0; j < 8; ++j) r[j] = f2bf(src[i+j]);
  *(bf16x8*)(dst + i) = *(bf16x8*)r;
}

// Wk [L][768][768] fp32 -> rows 768..1535 of wqkv [L][2304][768] bf16
__global__ void convert_wk_kernel(const float* __restrict__ wk, __bf16* __restrict__ wqkv) {
  size_t i = ((size_t)blockIdx.x*256 + threadIdx.x)*8;
  int l = (int)(i / (D_*D_));
  int rem = (int)(i % (D_*D_));
  int n = rem / D_, k = rem % D_;
  __bf16 r[8];
#pragma unroll
  for (int j = 0; j < 8; ++j) r[j] = f2bf(wk[i+j]);
  *(bf16x8*)(wqkv + (size_t)l*2304*D_ + (size_t)(768+n)*D_ + k) = *(bf16x8*)r;
}

// ---------------- TT adapter build: Wq_a / Wv_a -> wqkv bf16 ----------------
__global__ void tt_prep_kernel(
    const float* __restrict__ qc0, const float* __restrict__ qc1, const float* __restrict__ qc2,
    const float* __restrict__ qc3, const float* __restrict__ qc4, const float* __restrict__ qc5,
    const float* __restrict__ vc0, const float* __restrict__ vc1, const float* __restrict__ vc2,
    const float* __restrict__ vc3, const float* __restrict__ vc4, const float* __restrict__ vc5,
    const float* __restrict__ Wq, const float* __restrict__ Wv,
    const int* __restrict__ e_idx, __bf16* __restrict__ wqkv) {
  const int l = blockIdx.x;
  const int pre = blockIdx.y;         // 0 = q, 1 = v
  const int z = blockIdx.z;           // 0..15 -> rows 48z..48z+47
  const int tid = threadIdx.x;
  const int e = e_idx[0];
  const float* c0 = (pre ? vc0 : qc0) + (size_t)(e*L_ + l)*96;   // [12][8]
  const float* c1 = (pre ? vc1 : qc1) + (size_t)(e*L_ + l)*512;  // [8][8][8]
  const float* c2 = (pre ? vc2 : qc2) + (size_t)(e*L_ + l)*512;
  const float* c3 = (pre ? vc3 : qc3) + (size_t)(e*L_ + l)*512;
  const float* c4 = (pre ? vc4 : qc4) + (size_t)(e*L_ + l)*512;
  const float* c5 = (pre ? vc5 : qc5) + (size_t)(e*L_ + l)*96;   // [8][12]
  __shared__ float M1[768];   // [j][l2][m]
  __shared__ float R2[768];   // [q][r][t]
  __shared__ float M2[6144];  // [out][o]
  __shared__ float Rm[6144];  // [o][in]
  for (int idx = tid; idx < 768; idx += 256) {
    int j = idx >> 6, rem = idx & 63, l2 = rem >> 3, m = rem & 7;
    float s = 0.f;
    for (int k = 0; k < 8; ++k) s += c0[j*8 + k] * c1[k*64 + l2*8 + m];
    M1[idx] = s;
    int qq = idx / 96, rem2 = idx % 96, rr = rem2 / 12, t = rem2 % 12;
    float s2 = 0.f;
    for (int si = 0; si < 8; ++si) s2 += c4[qq*64 + rr*8 + si] * c5[si*12 + t];
    R2[idx] = s2;
  }
  __syncthreads();
  for (int idx = tid; idx < 6144; idx += 256) {
    int o = idx & 7, n = (idx >> 3) & 7, jl = idx >> 6;
    float s = 0.f;
    for (int m = 0; m < 8; ++m) s += M1[jl*8 + m] * c2[m*64 + n*8 + o];
    M2[idx] = s;
    int o2 = idx / 768, inp = idx % 768, p = inp / 96, rt = inp % 96;
    float s2 = 0.f;
    for (int qq = 0; qq < 8; ++qq) s2 += c3[o2*64 + p*8 + qq] * R2[qq*96 + rt];
    Rm[idx] = s2;
  }
  __syncthreads();
  const float* Wbase = (pre ? Wv : Wq) + (size_t)l*D_*D_;
  __bf16* dst = wqkv + (size_t)l*2304*D_ + (pre ? (size_t)1536*D_ : 0);
  for (int g = tid; g < 48*96; g += 256) {
    const int outr = z*48 + (g / 96);
    const int inp0 = (g % 96) * 8;
    float m2r[8];
#pragma unroll
    for (int o = 0; o < 8; ++o) m2r[o] = M2[outr*8 + o];
    float acc[8];
#pragma unroll
    for (int u = 0; u < 8; ++u) acc[u] = 0.f;
#pragma unroll
    for (int o = 0; o < 8; ++o) {
      float4 r0 = *(const float4*)&Rm[o*768 + inp0];
      float4 r1 = *(const float4*)&Rm[o*768 + inp0 + 4];
      acc[0] += m2r[o]*r0.x; acc[1] += m2r[o]*r0.y;
      acc[2] += m2r[o]*r0.z; acc[3] += m2r[o]*r0.w;
      acc[4] += m2r[o]*r1.x; acc[5] += m2r[o]*r1.y;
      acc[6] += m2r[o]*r1.z; acc[7] += m2r[o]*r1.w;
    }
    const float* wb = Wbase + (size_t)outr*768 + inp0;
    float4 w0 = *(const float4*)wb;
    float4 w1 = *(const float4*)(wb + 4);
    __bf16 r[8];
    r[0] = f2bf(w0.x + 8.f*acc[0]); r[1] = f2bf(w0.y + 8.f*acc[1]);
    r[2] = f2bf(w0.z + 8.f*acc[2]); r[3] = f2bf(w0.w + 8.f*acc[3]);
    r[4] = f2bf(w1.x + 8.f*acc[4]); r[5] = f2bf(w1.y + 8.f*acc[5]);
    r[6] = f2bf(w1.z + 8.f*acc[6]); r[7] = f2bf(w1.w + 8.f*acc[7]);
    *(bf16x8*)(dst + (size_t)outr*768 + inp0) = *(bf16x8*)r;
  }
}

// ---------------- bf16 MFMA GEMM: C[M][Nw] = A[M][768] * Bw[Nw][768]^T + bias ----------------
// OUTBF path (QKV gemm): blocks x<12 write q/k into qkv; x>=12 write V transposed into vt.
template<bool OUTBF>
__global__ __launch_bounds__(256) void gemm_bt(
    const __bf16* __restrict__ A, const __bf16* __restrict__ Bw,
    const float* __restrict__ bq, const float* __restrict__ bk, const float* __restrict__ bvp,
    __bf16* __restrict__ outb, float* __restrict__ outf, __bf16* __restrict__ vtout, int Nw) {
  const int K = D_;
  __shared__ __align__(16) __bf16 As[128*64];
  __shared__ __align__(16) __bf16 Bs[128*64];
  const int tid = threadIdx.x;
  const int w = tid >> 6, lane = tid & 63;
  const int quad = lane >> 4, l16 = lane & 15;
  const int wr = w >> 1, wc = w & 1;
  const size_t mblk = (size_t)blockIdx.y * 128;
  const size_t nblk = (size_t)blockIdx.x * 128;
  const __bf16* Ab = A + mblk * K;
  const __bf16* Bb = Bw + nblk * K;
  const int lrow = lane >> 3;        // 0..7
  const int scol = (lane & 7) * 8;   // element offset in K
  floatx4 acc[4][4];
#pragma unroll
  for (int i = 0; i < 4; ++i)
#pragma unroll
    for (int j = 0; j < 4; ++j) acc[i][j] = {0.f,0.f,0.f,0.f};

  for (int k0 = 0; k0 < K; k0 += 64) {
    __syncthreads();
#pragma unroll
    for (int i = 0; i < 4; ++i) {
      const int chunk = w*4 + i;           // wave-uniform
      const int row = chunk*8 + lrow;
      async16(Ab + (size_t)row*K + k0 + scol, &As[chunk*512]);
      async16(Bb + (size_t)row*K + k0 + scol, &Bs[chunk*512]);
    }
    __syncthreads();
#pragma unroll
    for (int kk = 0; kk < 64; kk += 32) {
      bf16x8 af[4], bfr[4];
#pragma unroll
      for (int i = 0; i < 4; ++i) af[i]  = *(const bf16x8*)&As[(wr*64 + i*16 + l16)*64 + kk + quad*8];
#pragma unroll
      for (int j = 0; j < 4; ++j) bfr[j] = *(const bf16x8*)&Bs[(wc*64 + j*16 + l16)*64 + kk + quad*8];
#pragma unroll
      for (int i = 0; i < 4; ++i)
#pragma unroll
        for (int j = 0; j < 4; ++j)
          acc[i][j] = __builtin_amdgcn_mfma_f32_16x16x32_bf16(af[i], bfr[j], acc[i][j], 0, 0, 0);
    }
  }
  if (OUTBF && blockIdx.x >= 12) {
    // V block: bias + transpose-write straight into vt[bh][64][512]
#pragma unroll
    for (int j = 0; j < 4; ++j) {
      const int vcol = (int)nblk - 1536 + wc*64 + j*16 + l16;   // 0..767
      const int h = vcol >> 6, d = vcol & 63;
      const float bval = bvp[vcol];
#pragma unroll
      for (int i = 0; i < 4; ++i) {
        const int mrow = (int)mblk + wr*64 + i*16 + quad*4;     // r=0 base
        const int b = mrow >> 9, s = mrow & 511;
        __bf16 pr[4];
#pragma unroll
        for (int r = 0; r < 4; ++r) pr[r] = f2bf(acc[i][j][r] + bval);
        *(bf16x4*)(vtout + (size_t)((b*H_ + h)*64 + d)*S_ + s) = *(bf16x4*)pr;
      }
    }
    return;
  }
  const float* bias = bq;
  if (Nw == 2304) bias = (blockIdx.x < 6) ? bq : bk;
#pragma unroll
  for (int i = 0; i < 4; ++i) {
#pragma unroll
    for (int j = 0; j < 4; ++j) {
      const int ncol = (int)nblk + wc*64 + j*16 + l16;
      const float bval = bias[ncol % 768];
#pragma unroll
      for (int r = 0; r < 4; ++r) {
        const int mrow = (int)mblk + wr*64 + i*16 + quad*4 + r;
        float v = acc[i][j][r] + bval;
        if (OUTBF) outb[(size_t)mrow*Nw + ncol] = f2bf(v);
        else       outf[(size_t)mrow*Nw + ncol] = v;
      }
    }
  }
}

// ---------------- flash attention v2: S^T-mfma, padded LDS, XCD swizzle ----------------
// 1-D grid of 3072: n&7 selects XCD-slot; bh = (n>>6)*8 + (n&7); qtile = (n>>3)&7.
#define PSTR 72   // padded LDS row stride (bf16): 144 B -> bank-even b128 access
__global__ __launch_bounds__(256) void flash_kernel(const __bf16* __restrict__ qkv,
                                                    const __bf16* __restrict__ vt,
                                                    __bf16* __restrict__ ctx) {
  __shared__ __align__(16) __bf16 Qs[64*PSTR];    // [q][d]
  __shared__ __align__(16) __bf16 Ks[64*PSTR];    // [kv][d]
  __shared__ __align__(16) __bf16 Vts[64*PSTR];   // [d][kv]
  __shared__ __align__(16) __bf16 Ps[64*PSTR];    // [q][kv], wave w owns rows w*16..+15
  const int tid = threadIdx.x;
  const int w = tid >> 6, lane = tid & 63;
  const int quad = lane >> 4, l16 = lane & 15;
  const int n = blockIdx.x;
  const int bh = (n >> 6)*8 + (n & 7);
  const int q0 = ((n >> 3) & 7) * 64;
  const int b = bh / H_, h = bh % H_;
  const float SCL = 0.125f * 1.44269504f;  // 1/sqrt(64) * log2(e)

  {
#pragma unroll
    for (int it = 0; it < 2; ++it) {
      int slot = it*256 + tid, row = slot >> 3, seg = slot & 7;
      bf16x8 v = *(const bf16x8*)(qkv + (size_t)(b*S_ + q0 + row)*2304 + h*64 + seg*8);
      *(bf16x8*)&Qs[row*PSTR + seg*8] = v;
    }
  }

  floatx4 acc_o[4];   // C[m=q_local=quad*4+r][n=d=jd*16+l16]
#pragma unroll
  for (int jd = 0; jd < 4; ++jd) acc_o[jd] = {0.f,0.f,0.f,0.f};
  float m_prev = -__builtin_inff();   // per-lane q = w*16 + l16 (log2 domain)
  float l_part = 0.f;                 // per-quad partial of the softmax denom

  for (int kt = 0; kt < 8; ++kt) {
    __syncthreads();
#pragma unroll
    for (int it = 0; it < 2; ++it) {
      int slot = it*256 + tid, row = slot >> 3, seg = slot & 7;
      bf16x8 kvv = *(const bf16x8*)(qkv + (size_t)(b*S_ + kt*64 + row)*2304 + 768 + h*64 + seg*8);
      bf16x8 vtv = *(const bf16x8*)(vt + (size_t)(bh*64 + row)*S_ + kt*64 + seg*8);
      *(bf16x8*)&Ks[row*PSTR + seg*8] = kvv;
      *(bf16x8*)&Vts[row*PSTR + seg*8] = vtv;
    }
    __syncthreads();
    // S^T tile: mfma(A=K, B=Q) -> C[m=kv=i*16+quad*4+r][n=q=w*16+l16]
    floatx4 sacc[4];
#pragma unroll
    for (int i = 0; i < 4; ++i) sacc[i] = {0.f,0.f,0.f,0.f};
#pragma unroll
    for (int kk = 0; kk < 64; kk += 32) {
      bf16x8 bq_ = *(const bf16x8*)&Qs[(w*16 + l16)*PSTR + kk + quad*8];
#pragma unroll
      for (int i = 0; i < 4; ++i) {
        bf16x8 ak = *(const bf16x8*)&Ks[(i*16 + l16)*PSTR + kk + quad*8];
        sacc[i] = __builtin_amdgcn_mfma_f32_16x16x32_bf16(ak, bq_, sacc[i], 0, 0, 0);
      }
    }
    float sv[4][4];
#pragma unroll
    for (int i = 0; i < 4; ++i)
#pragma unroll
      for (int r = 0; r < 4; ++r) sv[i][r] = sacc[i][r] * SCL;
    float mloc = sv[0][0];
#pragma unroll
    for (int i = 0; i < 4; ++i)
#pragma unroll
      for (int r = 0; r < 4; ++r) mloc = fmaxf(mloc, sv[i][r]);
    mloc = fmaxf(mloc, __shfl_xor(mloc, 16));
    mloc = fmaxf(mloc, __shfl_xor(mloc, 32));
    float mnew = fmaxf(m_prev, mloc);
    float alpha = fexp2(m_prev - mnew);
    m_prev = mnew;
    float rsum = 0.f;
#pragma unroll
    for (int i = 0; i < 4; ++i) {
      __bf16 pr[4];
#pragma unroll
      for (int r = 0; r < 4; ++r) {
        float p = fexp2(sv[i][r] - mnew);
        rsum += p;
        pr[r] = f2bf(p);
      }
      *(bf16x4*)&Ps[(w*16 + l16)*PSTR + i*16 + quad*4] = *(bf16x4*)pr;  // b64, bank-even
    }
    l_part = l_part*alpha + rsum;
    float ab[4];
#pragma unroll
    for (int r = 0; r < 4; ++r) ab[r] = __shfl(alpha, quad*4 + r);
#pragma unroll
    for (int jd = 0; jd < 4; ++jd)
#pragma unroll
      for (int r = 0; r < 4; ++r) acc_o[jd][r] *= ab[r];
    // O += P V : same-wave ds write->read is in-order
#pragma unroll
    for (int kk = 0; kk < 64; kk += 32) {
      bf16x8 ap = *(const bf16x8*)&Ps[(w*16 + l16)*PSTR + kk + quad*8];
#pragma unroll
      for (int jd = 0; jd < 4; ++jd) {
        bf16x8 bv_ = *(const bf16x8*)&Vts[(jd*16 + l16)*PSTR + kk + quad*8];
        acc_o[jd] = __builtin_amdgcn_mfma_f32_16x16x32_bf16(ap, bv_, acc_o[jd], 0, 0, 0);
      }
    }
  }
  float l_tot = l_part;
  l_tot += __shfl_xor(l_tot, 16);
  l_tot += __shfl_xor(l_tot, 32);
  float lb[4];
#pragma unroll
  for (int r = 0; r < 4; ++r) lb[r] = __shfl(l_tot, quad*4 + r);
#pragma unroll
  for (int jd = 0; jd < 4; ++jd) {
    const int d = jd*16 + l16;
#pragma unroll
    for (int r = 0; r < 4; ++r) {
      const int q = q0 + w*16 + quad*4 + r;
      ctx[(size_t)(b*S_ + q)*D_ + h*64 + d] = f2bf(acc_o[jd][r] / lb[r]);
    }
  }
}

// ---------------- residual + LayerNorm (fp32), writes fp32 master + bf16 copy ----------------
__global__ __launch_bounds__(256) void ln_kernel(const float* __restrict__ resid,
                                                 const float* __restrict__ proj,
                                                 const float* __restrict__ gamma,
                                                 const float* __restrict__ beta,
                                                 float* __restrict__ xout,
                                                 __bf16* __restrict__ xbf) {
  const int row = blockIdx.x;
  const int tid = threadIdx.x;
  const int w = tid >> 6, lane = tid & 63;
  __shared__ float red[4];
  float v[3]; int dd[3];
#pragma unroll
  for (int i = 0; i < 3; ++i) {
    int d = tid + i*256; dd[i] = d;
    v[i] = resid[(size_t)row*D_ + d] + proj[(size_t)row*D_ + d];
  }
  float s = v[0] + v[1] + v[2];
#pragma unroll
  for (int off = 32; off; off >>= 1) s += __shfl_xor(s, off);
  if (lane == 0) red[w] = s;
  __syncthreads();
  float mu = (red[0]+red[1]+red[2]+red[3]) * (1.f/768.f);
  __syncthreads();
  float q = 0.f;
#pragma unroll
  for (int i = 0; i < 3; ++i) { float d = v[i]-mu; q += d*d; }
#pragma unroll
  for (int off = 32; off; off >>= 1) q += __shfl_xor(q, off);
  if (lane == 0) red[w] = q;
  __syncthreads();
  float var = (red[0]+red[1]+red[2]+red[3]) * (1.f/768.f);
  float rs = rsqrtf(var + 1e-12f);
#pragma unroll
  for (int i = 0; i < 3; ++i) {
    float o = (v[i]-mu)*rs*gamma[dd[i]] + beta[dd[i]];
    xout[(size_t)row*D_ + dd[i]] = o;
    xbf[(size_t)row*D_ + dd[i]] = f2bf(o);
  }
}

extern "C" void kernel_launch(void* const* d_in, const int* in_sizes, int n_in,
                              void* d_out, int out_size, void* d_ws, size_t ws_size,
                              hipStream_t stream) {
  const float* hidden = (const float*)d_in[0];
  const float* router = (const float*)d_in[1];
  const float* qc[6]; const float* vc[6];
  for (int i = 0; i < 6; ++i) qc[i] = (const float*)d_in[2+i];
  for (int i = 0; i < 6; ++i) vc[i] = (const float*)d_in[8+i];
  const float* Wq = (const float*)d_in[14];
  const float* Wk = (const float*)d_in[15];
  const float* Wv = (const float*)d_in[16];
  const float* Wo = (const float*)d_in[17];
  const float* bq = (const float*)d_in[18];
  const float* bk = (const float*)d_in[19];
  const float* bv = (const float*)d_in[20];
  const float* bo = (const float*)d_in[21];
  const float* lns = (const float*)d_in[22];
  const float* lnb = (const float*)d_in[23];
  float* out = (float*)d_out;

  char* ws = (char*)d_ws;
  size_t off = 0;
  auto alloc = [&](size_t bytes) -> void* {
    off = (off + 255) & ~(size_t)255;
    void* p = ws + off; off += bytes; return p;
  };
  int*    e_idx = (int*)   alloc(4);
  float*  rpart = (float*) alloc((size_t)64*D_*4);
  __bf16* xbf   = (__bf16*)alloc((size_t)BS_*D_*2);
  __bf16* qkv   = (__bf16*)alloc((size_t)BS_*2304*2);
  __bf16* vt    = (__bf16*)alloc((size_t)B_*H_*64*S_*2);
  __bf16* ctx   = (__bf16*)alloc((size_t)BS_*D_*2);
  float*  proj  = (float*) alloc((size_t)BS_*D_*4);
  __bf16* wqkv  = (__bf16*)alloc((size_t)L_*2304*D_*2);
  __bf16* wobf  = (__bf16*)alloc((size_t)L_*D_*D_*2);
  (void)ws_size; (void)in_sizes; (void)n_in; (void)out_size;

  routing_pool_kernel<<<64, 256, 0, stream>>>(hidden, rpart);
  routing_finish_kernel<<<1, 256, 0, stream>>>(rpart, router, e_idx);
  convert_bf16_kernel<<<(BS_*D_)/2048, 256, 0, stream>>>(hidden, xbf);
  tt_prep_kernel<<<dim3(L_, 2, 16), 256, 0, stream>>>(qc[0],qc[1],qc[2],qc[3],qc[4],qc[5],
                                                      vc[0],vc[1],vc[2],vc[3],vc[4],vc[5],
                                                      Wq, Wv, e_idx, wqkv);
  convert_wk_kernel<<<(L_*D_*D_)/2048, 256, 0, stream>>>(Wk, wqkv);
  convert_bf16_kernel<<<(L_*D_*D_)/2048, 256, 0, stream>>>(Wo, wobf);

  for (int l = 0; l < L_; ++l) {
    gemm_bt<true><<<dim3(18,128), 256, 0, stream>>>(xbf, wqkv + (size_t)l*2304*D_,
        bq + l*D_, bk + l*D_, bv + l*D_, qkv, nullptr, vt, 2304);
    flash_kernel<<<3072, 256, 0, stream>>>(qkv, vt, ctx);
    gemm_bt<false><<<dim3(6,128), 256, 0, stream>>>(ctx, wobf + (size_t)l*D_*D_,
        bo + l*D_, nullptr, nullptr, nullptr, proj, nullptr, 768);
    ln_kernel<<<BS_, 256, 0, stream>>>(l == 0 ? hidden : out, proj,
        lns + l*D_, lnb + l*D_, out, xbf);
  }
}